// Round 4
// baseline (17.985 us; speedup 1.0000x reference)
//
#include <hip/hip_runtime.h>
#include <math.h>

namespace {
constexpr int NFACES = 384;
constexpr int IMG    = 256;
constexpr int CROP0  = 16;
constexpr int CROPN  = 224;
constexpr int NPIX   = CROPN * CROPN;       // 50176
constexpr int TILE   = 8;                   // 8x8 pixel tiles
constexpr int TILES_X = CROPN / TILE;       // 28
constexpr int NTILES  = TILES_X * TILES_X;  // 784
constexpr float INV_SIGMA = 1e5f;
constexpr float INV_GAMMA = 1e5f;
constexpr float EPSV  = 1e-4f;
constexpr float NEARV = 0.1f;
constexpr float FARV  = 100.0f;
constexpr float INV_FMN = 1.0f / (FARV - NEARV);
constexpr float THRESH = 1.1512915464633e-04f;  // SIGMA*ln(1/DIST_EPS - 1)
constexpr float RADIUS = 0.0118f;               // sqrt(THRESH) + margin
// d_ws layout: [0..384) float4 expanded bboxes; [384..384+384*7) float4 records
}

__device__ __forceinline__ float clamp01(float x) {
  return fminf(fmaxf(x, 0.0f), 1.0f);
}

struct Rec {
  float4 A, B, C, D, T0, T1, T2;
};

__device__ __forceinline__ Rec load_rec(const float4* __restrict__ recs, int f) {
  const float4* R = recs + 384 + f * 7;
  Rec r;
  r.A = R[0]; r.B = R[1]; r.C = R[2]; r.D = R[3];
  r.T0 = R[4]; r.T1 = R[5]; r.T2 = R[6];
  return r;
}

// ---- Kernel A: build per-face bbox + record table in d_ws ----
__global__ __launch_bounds__(64) void build_records(
    const float* __restrict__ g_faces, const float* __restrict__ g_tex,
    float4* __restrict__ ws) {
  int f = blockIdx.x * 64 + threadIdx.x;   // grid = 6 blocks, covers 384 exactly
  const float* gv = g_faces + f * 9;
  const float* gt = g_tex + f * 9;
  float x0 = gv[0], y0 = gv[1], z0 = gv[2];
  float x1 = gv[3], y1 = gv[4], z1 = gv[5];
  float x2 = gv[6], y2 = gv[7], z2 = gv[8];

  float bxmin = fminf(x0, fminf(x1, x2)) - RADIUS;
  float bxmax = fmaxf(x0, fmaxf(x1, x2)) + RADIUS;
  float bymin = fminf(y0, fminf(y1, y2)) - RADIUS;
  float bymax = fmaxf(y0, fmaxf(y1, y2)) + RADIUS;
  ws[f] = make_float4(bxmin, bxmax, bymin, bymax);

  float den = (y1 - y2) * (x0 - x2) + (x2 - x1) * (y0 - y2);
  if (fabsf(den) < 1e-10f) den = (den < 0.0f) ? -1e-10f : 1e-10f;
  float dinv = 1.0f / den;
  float e01 = (x1 - x0) * (x1 - x0) + (y1 - y0) * (y1 - y0);
  float e12 = (x2 - x1) * (x2 - x1) + (y2 - y1) * (y2 - y1);
  float e20 = (x0 - x2) * (x0 - x2) + (y0 - y2) * (y0 - y2);

  float4* R = ws + 384 + f * 7;
  R[0] = make_float4(x0, y0, x1, y1);
  R[1] = make_float4(x2, y2, 1.0f / z0, 1.0f / z1);
  R[2] = make_float4(1.0f / z2, (y1 - y2) * dinv, (x2 - x1) * dinv,
                     (y2 - y0) * dinv);
  R[3] = make_float4((x0 - x2) * dinv, 1.0f / fmaxf(e01, 1e-12f),
                     1.0f / fmaxf(e12, 1e-12f), 1.0f / fmaxf(e20, 1e-12f));
  R[4] = make_float4(gt[0], gt[1], gt[2], gt[3]);
  R[5] = make_float4(gt[4], gt[5], gt[6], gt[7]);
  R[6] = make_float4(gt[8], 0.0f, 0.0f, 0.0f);
}

// ---- Kernel B: one wave per 8x8 tile, no barriers ----
__global__ __launch_bounds__(64) void softras_tile(
    const float4* __restrict__ recs, float* __restrict__ d_out) {
  __shared__ unsigned short slist[NFACES];

  int lane  = threadIdx.x;
  int tileX = blockIdx.x % TILES_X;
  int tileY = blockIdx.x / TILES_X;

  float x_lo = (2.0f * (tileX * TILE + CROP0) + 1.0f) * (1.0f / IMG) - 1.0f;
  float x_hi = x_lo + (TILE - 1) * (2.0f / IMG);
  float y_hi = (2.0f * (IMG - 1 - (tileY * TILE + CROP0)) + 1.0f) * (1.0f / IMG) - 1.0f;
  float y_lo = y_hi - (TILE - 1) * (2.0f / IMG);

  // ---- binning: prefetch 6 bbox quads, then 6 ballot-compaction rounds ----
  float4 bb0 = recs[0 * 64 + lane];
  float4 bb1 = recs[1 * 64 + lane];
  float4 bb2 = recs[2 * 64 + lane];
  float4 bb3 = recs[3 * 64 + lane];
  float4 bb4 = recs[4 * 64 + lane];
  float4 bb5 = recs[5 * 64 + lane];

  unsigned long long lanemask = (1ull << lane) - 1ull;
  int base = 0;
  {
    float4 b = bb0;
    bool pred = (b.x <= x_hi) && (b.y >= x_lo) && (b.z <= y_hi) && (b.w >= y_lo);
    unsigned long long bal = __ballot(pred);
    if (pred) slist[base + __popcll(bal & lanemask)] = (unsigned short)(0 * 64 + lane);
    base += __popcll(bal);
  }
  {
    float4 b = bb1;
    bool pred = (b.x <= x_hi) && (b.y >= x_lo) && (b.z <= y_hi) && (b.w >= y_lo);
    unsigned long long bal = __ballot(pred);
    if (pred) slist[base + __popcll(bal & lanemask)] = (unsigned short)(1 * 64 + lane);
    base += __popcll(bal);
  }
  {
    float4 b = bb2;
    bool pred = (b.x <= x_hi) && (b.y >= x_lo) && (b.z <= y_hi) && (b.w >= y_lo);
    unsigned long long bal = __ballot(pred);
    if (pred) slist[base + __popcll(bal & lanemask)] = (unsigned short)(2 * 64 + lane);
    base += __popcll(bal);
  }
  {
    float4 b = bb3;
    bool pred = (b.x <= x_hi) && (b.y >= x_lo) && (b.z <= y_hi) && (b.w >= y_lo);
    unsigned long long bal = __ballot(pred);
    if (pred) slist[base + __popcll(bal & lanemask)] = (unsigned short)(3 * 64 + lane);
    base += __popcll(bal);
  }
  {
    float4 b = bb4;
    bool pred = (b.x <= x_hi) && (b.y >= x_lo) && (b.z <= y_hi) && (b.w >= y_lo);
    unsigned long long bal = __ballot(pred);
    if (pred) slist[base + __popcll(bal & lanemask)] = (unsigned short)(4 * 64 + lane);
    base += __popcll(bal);
  }
  {
    float4 b = bb5;
    bool pred = (b.x <= x_hi) && (b.y >= x_lo) && (b.z <= y_hi) && (b.w >= y_lo);
    unsigned long long bal = __ballot(pred);
    if (pred) slist[base + __popcll(bal & lanemask)] = (unsigned short)(5 * 64 + lane);
    base += __popcll(bal);
  }
  const int L = base;

  // ---- per-pixel accumulation (1 lane = 1 pixel) ----
  int px = lane & 7, py = lane >> 3;
  float qx = x_lo + px * (2.0f / IMG);
  float qy = y_hi - py * (2.0f / IMG);

  float m = EPSV;
  float sum_ew = 0.0f, sum_r = 0.0f, sum_g = 0.0f, sum_b = 0.0f;
  float aprod = 1.0f;

  if (L > 0) {
    Rec cur = load_rec(recs, slist[0]);
    for (int j = 0; j < L; ++j) {
      // branch-free prefetch of next record (re-loads last on final iter)
      int jn = j + 1 < L ? j + 1 : L - 1;
      Rec nxt = load_rec(recs, slist[jn]);

      float qa0x = qx - cur.A.x, qa0y = qy - cur.A.y;
      float qa1x = qx - cur.A.z, qa1y = qy - cur.A.w;
      float qa2x = qx - cur.B.x, qa2y = qy - cur.B.y;

      float w0 = cur.C.y * qa2x + cur.C.z * qa2y;
      float w1 = cur.C.w * qa2x + cur.D.x * qa2y;
      float w2 = 1.0f - w0 - w1;
      bool inside = (w0 >= 0.0f) && (w1 >= 0.0f) && (w2 >= 0.0f);

      float ex = qa0x - qa1x, ey = qa0y - qa1y;
      float tt = clamp01((qa0x * ex + qa0y * ey) * cur.D.y);
      float dx = qa0x - tt * ex, dy = qa0y - tt * ey;
      float d2min = dx * dx + dy * dy;

      ex = qa1x - qa2x; ey = qa1y - qa2y;
      tt = clamp01((qa1x * ex + qa1y * ey) * cur.D.z);
      dx = qa1x - tt * ex; dy = qa1y - tt * ey;
      d2min = fminf(d2min, dx * dx + dy * dy);

      ex = qa2x - qa0x; ey = qa2y - qa0y;
      tt = clamp01((qa2x * ex + qa2y * ey) * cur.D.w);
      dx = qa2x - tt * ex; dy = qa2y - tt * ey;
      d2min = fminf(d2min, dx * dx + dy * dy);

      bool contrib = inside || (d2min <= THRESH);

      float wc0 = clamp01(w0), wc1 = clamp01(w1), wc2 = clamp01(w2);
      float invs = __builtin_amdgcn_rcpf(fmaxf(wc0 + wc1 + wc2, 1e-12f));
      wc0 *= invs; wc1 *= invs; wc2 *= invs;

      float zden = fmaxf(wc0 * cur.B.z + wc1 * cur.B.w + wc2 * cur.C.x, 1e-12f);
      float zp = 1.0f / zden;      // precise: feeds exp(x*1e5)
      bool valid = contrib && (zp >= NEARV) && (zp <= FARV);
      float zn = (FARV - zp) * INV_FMN;
      float zns = valid ? zn : 0.0f;

      float e = __expf(-d2min * INV_SIGMA);
      float r1pe = __builtin_amdgcn_rcpf(1.0f + e);
      float Dp = inside ? r1pe : e * r1pe;   // stable sigmoid

      float mnew = fmaxf(m, zns);
      float cor = __expf((m - mnew) * INV_GAMMA);
      float ew = valid ? Dp * __expf((zns - mnew) * INV_GAMMA) : 0.0f;

      float cr = wc0 * cur.T0.x + wc1 * cur.T0.w + wc2 * cur.T1.z;
      float cg = wc0 * cur.T0.y + wc1 * cur.T1.x + wc2 * cur.T1.w;
      float cb = wc0 * cur.T0.z + wc1 * cur.T1.y + wc2 * cur.T2.x;

      sum_ew = sum_ew * cor + ew;
      sum_r  = sum_r  * cor + ew * cr;
      sum_g  = sum_g  * cor + ew * cg;
      sum_b  = sum_b  * cor + ew * cb;
      aprod *= contrib ? (1.0f - Dp) : 1.0f;
      m = mnew;

      cur = nxt;
    }
  }

  int row = tileY * TILE + py;
  int col = tileX * TILE + px;
  int t = row * CROPN + col;
  float bg = __expf((EPSV - m) * INV_GAMMA);
  float inv_den = 1.0f / (sum_ew + bg);
  d_out[t] = 1.0f - aprod;              // rendered_seg
  float* dd = d_out + NPIX + t * 3;     // rendered_depth
  dd[0] = sum_r * inv_den;
  dd[1] = sum_g * inv_den;
  dd[2] = sum_b * inv_den;
}

extern "C" void kernel_launch(void* const* d_in, const int* in_sizes, int n_in,
                              void* d_out, int out_size, void* d_ws, size_t ws_size,
                              hipStream_t stream) {
  const float* faces = (const float*)d_in[0];  // (1,384,3,3)
  const float* tex   = (const float*)d_in[1];  // (1,384,3,3)
  float* out = (float*)d_out;                  // 50176 seg + 150528 depth
  float4* ws = (float4*)d_ws;                  // 384 bbox + 384*7 record quads

  build_records<<<NFACES / 64, 64, 0, stream>>>(faces, tex, ws);
  softras_tile<<<NTILES, 64, 0, stream>>>((const float4*)ws, out);
}

// Round 5
// 15.891 us; speedup vs baseline: 1.1318x; 1.1318x over previous
//
#include <hip/hip_runtime.h>
#include <math.h>

namespace {
constexpr int NFACES = 384;
constexpr int IMG    = 256;
constexpr int CROP0  = 16;
constexpr int CROPN  = 224;
constexpr int NPIX   = CROPN * CROPN;       // 50176
constexpr int TILE   = 8;                   // 8x8 pixel tiles
constexpr int TILES_X = CROPN / TILE;       // 28
constexpr int NTILES  = TILES_X * TILES_X;  // 784
constexpr int REC    = 28;                  // floats per record (112 B, 16B-aligned)
constexpr int RCHUNK = 128;                 // records per LDS chunk
constexpr float INV_SIGMA = 1e5f;
constexpr float INV_GAMMA = 1e5f;
constexpr float EPSV  = 1e-4f;
constexpr float NEARV = 0.1f;
constexpr float FARV  = 100.0f;
constexpr float INV_FMN = 1.0f / (FARV - NEARV);
constexpr float THRESH = 1.1512915464633e-04f;  // SIGMA*ln(1/DIST_EPS - 1)
constexpr float RADIUS = 0.0118f;               // sqrt(THRESH) + margin
}

__device__ __forceinline__ float clamp01(float x) {
  return fminf(fmaxf(x, 0.0f), 1.0f);
}

// One block = one 8x8 tile. 4 waves; each wave owns 16 pixels, 4-way face split.
__global__ __launch_bounds__(256) void softras_fused(
    const float* __restrict__ g_faces, const float* __restrict__ g_tex,
    float* __restrict__ d_out) {
  __shared__ unsigned short slist[NFACES];          // 768 B
  __shared__ __align__(16) float srec[RCHUNK * REC]; // 14336 B

  int tid  = threadIdx.x;
  int w    = tid >> 6;
  int lane = tid & 63;

  int tileX = blockIdx.x % TILES_X;
  int tileY = blockIdx.x / TILES_X;
  float x_lo = (2.0f * (tileX * TILE + CROP0) + 1.0f) * (1.0f / IMG) - 1.0f;
  float x_hi = x_lo + (TILE - 1) * (2.0f / IMG);
  float y_hi = (2.0f * (IMG - 1 - (tileY * TILE + CROP0)) + 1.0f) * (1.0f / IMG) - 1.0f;
  float y_lo = y_hi - (TILE - 1) * (2.0f / IMG);

  // ---- binning: every wave computes identical ballots (deterministic);
  //      only wave 0 writes the compacted list. L is wave-uniform & identical
  //      across waves, so later barriers have uniform trip counts. ----
  unsigned long long lm = (1ull << lane) - 1ull;
  int L = 0;
  #pragma unroll
  for (int r = 0; r < 6; ++r) {
    int f = r * 64 + lane;
    const float* gv = g_faces + f * 9;
    float fx0 = gv[0], fy0 = gv[1];
    float fx1 = gv[3], fy1 = gv[4];
    float fx2 = gv[6], fy2 = gv[7];
    float bxmin = fminf(fx0, fminf(fx1, fx2)) - RADIUS;
    float bxmax = fmaxf(fx0, fmaxf(fx1, fx2)) + RADIUS;
    float bymin = fminf(fy0, fminf(fy1, fy2)) - RADIUS;
    float bymax = fmaxf(fy0, fmaxf(fy1, fy2)) + RADIUS;
    bool pred = (bxmin <= x_hi) && (bxmax >= x_lo) &&
                (bymin <= y_hi) && (bymax >= y_lo);
    unsigned long long bal = __ballot(pred);
    if (w == 0 && pred) slist[L + __popcll(bal & lm)] = (unsigned short)f;
    L += __popcll(bal);
  }
  __syncthreads();

  // ---- per-pixel accumulation: wave w owns pixels w*16..w*16+15;
  //      4-way face split within each 16-lane pixel group ----
  int s  = lane >> 4;
  int p  = (w << 4) | (lane & 15);
  int px = p & 7, py = p >> 3;
  float qx = x_lo + px * (2.0f / IMG);
  float qy = y_hi - py * (2.0f / IMG);

  float m = EPSV;
  float sum_ew = 0.0f, sum_r = 0.0f, sum_g = 0.0f, sum_b = 0.0f;
  float aprod = 1.0f;

  for (int c = 0; c < L; c += RCHUNK) {
    int n = min(RCHUNK, L - c);
    // build records for this chunk (thread k -> record k), divisions here
    if (tid < n) {
      int f = slist[c + tid];
      const float* gv = g_faces + f * 9;
      const float* gq = g_tex + f * 9;
      float x0 = gv[0], y0 = gv[1], z0 = gv[2];
      float x1 = gv[3], y1 = gv[4], z1 = gv[5];
      float x2 = gv[6], y2 = gv[7], z2 = gv[8];
      float den = (y1 - y2) * (x0 - x2) + (x2 - x1) * (y0 - y2);
      if (fabsf(den) < 1e-10f) den = (den < 0.0f) ? -1e-10f : 1e-10f;
      float dinv = 1.0f / den;
      float e01 = (x1 - x0) * (x1 - x0) + (y1 - y0) * (y1 - y0);
      float e12 = (x2 - x1) * (x2 - x1) + (y2 - y1) * (y2 - y1);
      float e20 = (x0 - x2) * (x0 - x2) + (y0 - y2) * (y0 - y2);
      float4* R = reinterpret_cast<float4*>(&srec[tid * REC]);
      R[0] = make_float4(x0, y0, x1, y1);
      R[1] = make_float4(x2, y2, 1.0f / z0, 1.0f / z1);
      R[2] = make_float4(1.0f / z2, (y1 - y2) * dinv, (x2 - x1) * dinv,
                         (y2 - y0) * dinv);
      R[3] = make_float4((x0 - x2) * dinv, 1.0f / fmaxf(e01, 1e-12f),
                         1.0f / fmaxf(e12, 1e-12f), 1.0f / fmaxf(e20, 1e-12f));
      R[4] = make_float4(gq[0], gq[1], gq[2], gq[3]);
      R[5] = make_float4(gq[4], gq[5], gq[6], gq[7]);
      R[6] = make_float4(gq[8], 0.0f, 0.0f, 0.0f);
    }
    __syncthreads();

    for (int j = s; j < n; j += 4) {
      const float4* R = reinterpret_cast<const float4*>(&srec[j * REC]);
      float4 A  = R[0];  // x0,y0,x1,y1
      float4 B  = R[1];  // x2,y2,iz0,iz1
      float4 C  = R[2];  // iz2,e01,e02,e11
      float4 D  = R[3];  // e12,il01,il12,il20
      float4 T0 = R[4];
      float4 T1 = R[5];
      float4 T2 = R[6];

      float qa0x = qx - A.x, qa0y = qy - A.y;
      float qa1x = qx - A.z, qa1y = qy - A.w;
      float qa2x = qx - B.x, qa2y = qy - B.y;

      float w0 = C.y * qa2x + C.z * qa2y;
      float w1 = C.w * qa2x + D.x * qa2y;
      float w2 = 1.0f - w0 - w1;
      bool inside = (w0 >= 0.0f) && (w1 >= 0.0f) && (w2 >= 0.0f);

      float ex = qa0x - qa1x, ey = qa0y - qa1y;
      float tt = clamp01((qa0x * ex + qa0y * ey) * D.y);
      float dx = qa0x - tt * ex, dy = qa0y - tt * ey;
      float d2min = dx * dx + dy * dy;

      ex = qa1x - qa2x; ey = qa1y - qa2y;
      tt = clamp01((qa1x * ex + qa1y * ey) * D.z);
      dx = qa1x - tt * ex; dy = qa1y - tt * ey;
      d2min = fminf(d2min, dx * dx + dy * dy);

      ex = qa2x - qa0x; ey = qa2y - qa0y;
      tt = clamp01((qa2x * ex + qa2y * ey) * D.w);
      dx = qa2x - tt * ex; dy = qa2y - tt * ey;
      d2min = fminf(d2min, dx * dx + dy * dy);

      bool contrib = inside || (d2min <= THRESH);

      float wc0 = clamp01(w0), wc1 = clamp01(w1), wc2 = clamp01(w2);
      float invs = __builtin_amdgcn_rcpf(fmaxf(wc0 + wc1 + wc2, 1e-12f));
      wc0 *= invs; wc1 *= invs; wc2 *= invs;

      float zden = fmaxf(wc0 * B.z + wc1 * B.w + wc2 * C.x, 1e-12f);
      float zp = 1.0f / zden;        // precise: feeds exp(x*1e5)
      bool valid = contrib && (zp >= NEARV) && (zp <= FARV);
      float zn = (FARV - zp) * INV_FMN;
      float zns = valid ? zn : 0.0f;

      float e = __expf(-d2min * INV_SIGMA);
      float r1pe = __builtin_amdgcn_rcpf(1.0f + e);
      float Dp = inside ? r1pe : e * r1pe;   // stable sigmoid

      float mnew = fmaxf(m, zns);
      float cor = __expf((m - mnew) * INV_GAMMA);
      float ew = valid ? Dp * __expf((zns - mnew) * INV_GAMMA) : 0.0f;

      float cr = wc0 * T0.x + wc1 * T0.w + wc2 * T1.z;
      float cg = wc0 * T0.y + wc1 * T1.x + wc2 * T1.w;
      float cb = wc0 * T0.z + wc1 * T1.y + wc2 * T2.x;

      sum_ew = sum_ew * cor + ew;
      sum_r  = sum_r  * cor + ew * cr;
      sum_g  = sum_g  * cor + ew * cg;
      sum_b  = sum_b  * cor + ew * cb;
      aprod *= contrib ? (1.0f - Dp) : 1.0f;
      m = mnew;
    }
    __syncthreads();   // protect srec before next chunk's build
  }

  // ---- merge the 4 face sub-chunks (lane bits 4..5) ----
  #pragma unroll
  for (int mask = 16; mask <= 32; mask <<= 1) {
    float mo = __shfl_xor(m, mask);
    float so = __shfl_xor(sum_ew, mask);
    float ro = __shfl_xor(sum_r, mask);
    float go = __shfl_xor(sum_g, mask);
    float bo = __shfl_xor(sum_b, mask);
    float ao = __shfl_xor(aprod, mask);
    float mn = fmaxf(m, mo);
    float c1 = __expf((m - mn) * INV_GAMMA);
    float c2 = __expf((mo - mn) * INV_GAMMA);
    sum_ew = sum_ew * c1 + so * c2;
    sum_r  = sum_r  * c1 + ro * c2;
    sum_g  = sum_g  * c1 + go * c2;
    sum_b  = sum_b  * c1 + bo * c2;
    aprod *= ao;
    m = mn;
  }

  if (s == 0) {
    int row = tileY * TILE + py;
    int col = tileX * TILE + px;
    int t = row * CROPN + col;
    float bg = __expf((EPSV - m) * INV_GAMMA);
    float inv_den = 1.0f / (sum_ew + bg);
    d_out[t] = 1.0f - aprod;              // rendered_seg
    float* dd = d_out + NPIX + t * 3;     // rendered_depth
    dd[0] = sum_r * inv_den;
    dd[1] = sum_g * inv_den;
    dd[2] = sum_b * inv_den;
  }
}

extern "C" void kernel_launch(void* const* d_in, const int* in_sizes, int n_in,
                              void* d_out, int out_size, void* d_ws, size_t ws_size,
                              hipStream_t stream) {
  const float* faces = (const float*)d_in[0];  // (1,384,3,3)
  const float* tex   = (const float*)d_in[1];  // (1,384,3,3)
  float* out = (float*)d_out;                  // 50176 seg + 150528 depth
  softras_fused<<<NTILES, 256, 0, stream>>>(faces, tex, out);
}

// Round 6
// 10.761 us; speedup vs baseline: 1.6713x; 1.4767x over previous
//
#include <hip/hip_runtime.h>
#include <math.h>

namespace {
constexpr int NFACES = 384;
constexpr int IMG    = 256;
constexpr int CROP0  = 16;
constexpr int CROPN  = 224;
constexpr int NPIX   = CROPN * CROPN;       // 50176
constexpr int TILE   = 8;                   // 8x8 pixel tiles
constexpr int TILES_X = CROPN / TILE;       // 28
constexpr int NTILES  = TILES_X * TILES_X;  // 784
constexpr int NF4     = NFACES * 9 / 4;     // 864 float4 per input array
constexpr float INV_SIGMA = 1e5f;
constexpr float INV_GAMMA = 1e5f;
constexpr float EPSV  = 1e-4f;
constexpr float NEARV = 0.1f;
constexpr float FARV  = 100.0f;
constexpr float INV_FMN = 1.0f / (FARV - NEARV);
constexpr float THRESH = 1.1512915464633e-04f;  // SIGMA*ln(1/DIST_EPS - 1)
constexpr float RADIUS = 0.0118f;               // sqrt(THRESH) + margin
}

__device__ __forceinline__ float clamp01(float x) {
  return fminf(fmaxf(x, 0.0f), 1.0f);
}

// One block = one 8x8 tile. 4 waves; each wave owns 16 pixels, 4-way face split.
// All face/tex data staged coalesced into LDS; all derived math inline (rcpf).
__global__ __launch_bounds__(256) void softras_fused(
    const float* __restrict__ g_faces, const float* __restrict__ g_tex,
    float* __restrict__ d_out) {
  __shared__ __align__(16) float sface[NFACES * 9];   // 13824 B
  __shared__ __align__(16) float stex[NFACES * 9];    // 13824 B
  __shared__ unsigned short slist[NFACES];            // 768 B

  int tid  = threadIdx.x;
  int w    = tid >> 6;
  int lane = tid & 63;

  // ---- coalesced raw staging ----
  {
    const float4* gf4 = reinterpret_cast<const float4*>(g_faces);
    const float4* gt4 = reinterpret_cast<const float4*>(g_tex);
    float4* sf4 = reinterpret_cast<float4*>(sface);
    float4* st4 = reinterpret_cast<float4*>(stex);
    for (int i = tid; i < NF4; i += 256) {
      sf4[i] = gf4[i];
      st4[i] = gt4[i];
    }
  }

  int tileX = blockIdx.x % TILES_X;
  int tileY = blockIdx.x / TILES_X;
  float x_lo = (2.0f * (tileX * TILE + CROP0) + 1.0f) * (1.0f / IMG) - 1.0f;
  float x_hi = x_lo + (TILE - 1) * (2.0f / IMG);
  float y_hi = (2.0f * (IMG - 1 - (tileY * TILE + CROP0)) + 1.0f) * (1.0f / IMG) - 1.0f;
  float y_lo = y_hi - (TILE - 1) * (2.0f / IMG);

  __syncthreads();

  // ---- binning from LDS: every wave computes identical ballots; wave 0
  //      writes the compacted list. L identical across waves. ----
  unsigned long long lm = (1ull << lane) - 1ull;
  int L = 0;
  #pragma unroll
  for (int r = 0; r < 6; ++r) {
    int f = r * 64 + lane;
    const float* fv = &sface[f * 9];
    float fx0 = fv[0], fy0 = fv[1];
    float fx1 = fv[3], fy1 = fv[4];
    float fx2 = fv[6], fy2 = fv[7];
    float bxmin = fminf(fx0, fminf(fx1, fx2)) - RADIUS;
    float bxmax = fmaxf(fx0, fmaxf(fx1, fx2)) + RADIUS;
    float bymin = fminf(fy0, fminf(fy1, fy2)) - RADIUS;
    float bymax = fmaxf(fy0, fmaxf(fy1, fy2)) + RADIUS;
    bool pred = (bxmin <= x_hi) && (bxmax >= x_lo) &&
                (bymin <= y_hi) && (bymax >= y_lo);
    unsigned long long bal = __ballot(pred);
    if (w == 0 && pred) slist[L + __popcll(bal & lm)] = (unsigned short)f;
    L += __popcll(bal);
  }
  __syncthreads();

  // ---- per-pixel accumulation: wave w owns pixels w*16..w*16+15;
  //      4-way face split (s) within each 16-lane pixel group ----
  int s  = lane >> 4;
  int p  = (w << 4) | (lane & 15);
  int px = p & 7, py = p >> 3;
  float qx = x_lo + px * (2.0f / IMG);
  float qy = y_hi - py * (2.0f / IMG);

  float m = EPSV;
  float sum_ew = 0.0f, sum_r = 0.0f, sum_g = 0.0f, sum_b = 0.0f;
  float aprod = 1.0f;

  for (int j = s; j < L; j += 4) {
    int f = slist[j];
    const float* fv = &sface[f * 9];
    const float* tx = &stex[f * 9];
    float x0 = fv[0], y0 = fv[1], z0 = fv[2];
    float x1 = fv[3], y1 = fv[4], z1 = fv[5];
    float x2 = fv[6], y2 = fv[7], z2 = fv[8];

    float den = (y1 - y2) * (x0 - x2) + (x2 - x1) * (y0 - y2);
    if (fabsf(den) < 1e-10f) den = (den < 0.0f) ? -1e-10f : 1e-10f;
    float dinv = __builtin_amdgcn_rcpf(den);

    float qa2x = qx - x2, qa2y = qy - y2;
    float w0 = ((y1 - y2) * qa2x + (x2 - x1) * qa2y) * dinv;
    float w1 = ((y2 - y0) * qa2x + (x0 - x2) * qa2y) * dinv;
    float w2 = 1.0f - w0 - w1;
    bool inside = (w0 >= 0.0f) && (w1 >= 0.0f) && (w2 >= 0.0f);

    float qa0x = qx - x0, qa0y = qy - y0;
    float qa1x = qx - x1, qa1y = qy - y1;

    float ex = x1 - x0, ey = y1 - y0;
    float il = __builtin_amdgcn_rcpf(fmaxf(ex * ex + ey * ey, 1e-12f));
    float tt = clamp01((qa0x * ex + qa0y * ey) * il);
    float dx = qa0x - tt * ex, dy = qa0y - tt * ey;
    float d2min = dx * dx + dy * dy;

    ex = x2 - x1; ey = y2 - y1;
    il = __builtin_amdgcn_rcpf(fmaxf(ex * ex + ey * ey, 1e-12f));
    tt = clamp01((qa1x * ex + qa1y * ey) * il);
    dx = qa1x - tt * ex; dy = qa1y - tt * ey;
    d2min = fminf(d2min, dx * dx + dy * dy);

    ex = x0 - x2; ey = y0 - y2;
    il = __builtin_amdgcn_rcpf(fmaxf(ex * ex + ey * ey, 1e-12f));
    tt = clamp01((qa2x * ex + qa2y * ey) * il);
    dx = qa2x - tt * ex; dy = qa2y - tt * ey;
    d2min = fminf(d2min, dx * dx + dy * dy);

    bool contrib = inside || (d2min <= THRESH);

    float wc0 = clamp01(w0), wc1 = clamp01(w1), wc2 = clamp01(w2);
    float invs = __builtin_amdgcn_rcpf(fmaxf(wc0 + wc1 + wc2, 1e-12f));
    wc0 *= invs; wc1 *= invs; wc2 *= invs;

    float zden = wc0 * __builtin_amdgcn_rcpf(z0) +
                 wc1 * __builtin_amdgcn_rcpf(z1) +
                 wc2 * __builtin_amdgcn_rcpf(z2);
    float zp = __builtin_amdgcn_rcpf(fmaxf(zden, 1e-12f));
    bool valid = contrib && (zp >= NEARV) && (zp <= FARV);
    float zn = (FARV - zp) * INV_FMN;
    float zns = valid ? zn : 0.0f;

    float e = __expf(-d2min * INV_SIGMA);
    float r1pe = __builtin_amdgcn_rcpf(1.0f + e);
    float Dp = inside ? r1pe : e * r1pe;   // stable sigmoid

    float mnew = fmaxf(m, zns);
    float cor = __expf((m - mnew) * INV_GAMMA);
    float ew = valid ? Dp * __expf((zns - mnew) * INV_GAMMA) : 0.0f;

    float cr = wc0 * tx[0] + wc1 * tx[3] + wc2 * tx[6];
    float cg = wc0 * tx[1] + wc1 * tx[4] + wc2 * tx[7];
    float cb = wc0 * tx[2] + wc1 * tx[5] + wc2 * tx[8];

    sum_ew = sum_ew * cor + ew;
    sum_r  = sum_r  * cor + ew * cr;
    sum_g  = sum_g  * cor + ew * cg;
    sum_b  = sum_b  * cor + ew * cb;
    aprod *= contrib ? (1.0f - Dp) : 1.0f;
    m = mnew;
  }

  // ---- merge the 4 face sub-chunks (lane bits 4..5) ----
  #pragma unroll
  for (int mask = 16; mask <= 32; mask <<= 1) {
    float mo = __shfl_xor(m, mask);
    float so = __shfl_xor(sum_ew, mask);
    float ro = __shfl_xor(sum_r, mask);
    float go = __shfl_xor(sum_g, mask);
    float bo = __shfl_xor(sum_b, mask);
    float ao = __shfl_xor(aprod, mask);
    float mn = fmaxf(m, mo);
    float c1 = __expf((m - mn) * INV_GAMMA);
    float c2 = __expf((mo - mn) * INV_GAMMA);
    sum_ew = sum_ew * c1 + so * c2;
    sum_r  = sum_r  * c1 + ro * c2;
    sum_g  = sum_g  * c1 + go * c2;
    sum_b  = sum_b  * c1 + bo * c2;
    aprod *= ao;
    m = mn;
  }

  if (s == 0) {
    int row = tileY * TILE + py;
    int col = tileX * TILE + px;
    int t = row * CROPN + col;
    float bg = __expf((EPSV - m) * INV_GAMMA);
    float inv_den = 1.0f / (sum_ew + bg);
    d_out[t] = 1.0f - aprod;              // rendered_seg
    float* dd = d_out + NPIX + t * 3;     // rendered_depth
    dd[0] = sum_r * inv_den;
    dd[1] = sum_g * inv_den;
    dd[2] = sum_b * inv_den;
  }
}

extern "C" void kernel_launch(void* const* d_in, const int* in_sizes, int n_in,
                              void* d_out, int out_size, void* d_ws, size_t ws_size,
                              hipStream_t stream) {
  const float* faces = (const float*)d_in[0];  // (1,384,3,3)
  const float* tex   = (const float*)d_in[1];  // (1,384,3,3)
  float* out = (float*)d_out;                  // 50176 seg + 150528 depth
  softras_fused<<<NTILES, 256, 0, stream>>>(faces, tex, out);
}